// Round 7
// baseline (159.607 us; speedup 1.0000x reference)
//
#include <hip/hip_runtime.h>
#include <math.h>

#define BATCH 8
#define DIMD  512
#define NTOK  1024
#define NH    8
#define CQKV  640
#define DOUT  512

typedef __attribute__((ext_vector_type(8))) short short8;
typedef __attribute__((ext_vector_type(4))) short short4v;
typedef __attribute__((ext_vector_type(4))) float f32x4;

__device__ __forceinline__ short bf16rn(float x) {
    unsigned u = __float_as_uint(x);
    u += 0x7FFF + ((u >> 16) & 1);
    return (short)(u >> 16);
}
__device__ __forceinline__ float bf16tof(short s) {
    return __uint_as_float(((unsigned)(unsigned short)s) << 16);
}
struct HL { short h, l; };
__device__ __forceinline__ HL bf16split(float x) {
    HL r;
    r.h = bf16rn(x);
    r.l = bf16rn(x - bf16tof(r.h));
    return r;
}
__device__ __forceinline__ void dma16(const short* g, short* l) {
    __builtin_amdgcn_global_load_lds(
        (const __attribute__((address_space(1))) unsigned int*)g,
        (__attribute__((address_space(3))) unsigned int*)l, 16, 0, 0);
}
// pack (truncate) two f32 -> two bf16 in one dword (lo = f0, hi = f1)
__device__ __forceinline__ unsigned packbf2(float f0, float f1) {
    return __builtin_amdgcn_perm(__float_as_uint(f1), __float_as_uint(f0), 0x07060302);
}

// 16x16x16 bf16 MFMA (A,B: 4 bf16 = 2 VGPR); builtin name varies.
#if defined(__has_builtin)
#if __has_builtin(__builtin_amdgcn_mfma_f32_16x16x16bf16_1k)
#define HAVE_MFMA16_BUILTIN 1
__device__ __forceinline__ f32x4 mfma16(short4v a, short4v b, f32x4 c) {
    return __builtin_amdgcn_mfma_f32_16x16x16bf16_1k(a, b, c, 0, 0, 0);
}
#elif __has_builtin(__builtin_amdgcn_mfma_f32_16x16x16_bf16)
#define HAVE_MFMA16_BUILTIN 1
__device__ __forceinline__ f32x4 mfma16(short4v a, short4v b, f32x4 c) {
    return __builtin_amdgcn_mfma_f32_16x16x16_bf16(a, b, c, 0, 0, 0);
}
#endif
#endif
#ifndef HAVE_MFMA16_BUILTIN
__device__ __forceinline__ f32x4 mfma16(short4v a, short4v b, f32x4 c) {
    asm("s_nop 1\n\tv_mfma_f32_16x16x16_bf16 %0, %1, %2, %0"
        : "+v"(c) : "v"(a), "v"(b));
    return c;
}
#endif

// Fragment-order conventions (verified end-to-end R2/R4-R13, R19):
//  A-frag (16x16x32): lane=(q,r), element A[m=r][k=q*8+j]; B-frag identical.
//  A/B-frag (16x16x16): lane=(q,r), element [r][k=q*4+j], j=0..3.
//  C/D   : D[m=q*4+reg][ncol=r]
// K frag buffer: [b][t16][ic8][lane64][j8]; Q: [b][h][nt64][kc2][lane64][j8]
// V frag buffer (R20, 16x16x16 B-frag order): [b][t16][ic16][lane64][j4]
//   where ic = c4*4 + tv: element V[key=t*64+c4*16+(lane>>4)*4+j][v=tv*16+(lane&15)]
// O frag buffer:    [b][nt64][ct16][lane64][j8]

// ---------------------------------------------------------------------------
// prepack_all (unchanged from R13)
// ---------------------------------------------------------------------------
__global__ __launch_bounds__(256) void prepack_all(const float* __restrict__ x,
                                                   const float* __restrict__ qp,
                                                   const float* __restrict__ kp,
                                                   const float* __restrict__ vp,
                                                   const float* __restrict__ wout,
                                                   short* __restrict__ whi,
                                                   short* __restrict__ wlo,
                                                   short* __restrict__ xhi,
                                                   short* __restrict__ xlo,
                                                   short* __restrict__ wof) {
    __shared__ float Cs[64][65];
    const int blk = blockIdx.x;
    const int t = threadIdx.x;
    if (blk < 1024) {
        const int nt = blk & 15, dt = (blk >> 4) & 7, b = blk >> 7;
        #pragma unroll
        for (int i = 0; i < 4; ++i) {
            int row = (t >> 4) + i * 16;
            float4 v = *(const float4*)(x + ((size_t)(b * DIMD + dt * 64 + row)) * NTOK
                                          + nt * 64 + (t & 15) * 4);
            Cs[row][(t & 15) * 4 + 0] = v.x;
            Cs[row][(t & 15) * 4 + 1] = v.y;
            Cs[row][(t & 15) * 4 + 2] = v.z;
            Cs[row][(t & 15) * 4 + 3] = v.w;
        }
        __syncthreads();
        for (int u = t; u < 512; u += 256) {
            int lane2 = u & 63, cidx = u >> 6;
            int q2 = lane2 >> 4, r2 = lane2 & 15;
            int kt_loc = cidx & 1, mt_loc = cidx >> 1;
            short8 h8, l8;
            #pragma unroll
            for (int j = 0; j < 8; ++j) {
                HL s = bf16split(Cs[kt_loc * 32 + q2 * 8 + j][mt_loc * 16 + r2]);
                h8[j] = s.h; l8[j] = s.l;
            }
            size_t off = (((size_t)(b * 64 + nt * 4 + mt_loc)) * 16 + dt * 2 + kt_loc) * 512
                         + lane2 * 8;
            *(short8*)&xhi[off] = h8;
            *(short8*)&xlo[off] = l8;
        }
    } else if (blk < 1184) {
        int tid = (blk - 1024) * 256 + t;
        int lane = tid & 63, kt = (tid >> 6) & 15, ct = tid >> 10;
        int q = lane >> 4, r = lane & 15;
        int c = ct * 16 + r;
        short8 h, l;
        #pragma unroll
        for (int j = 0; j < 8; ++j) {
            int d = kt * 32 + q * 8 + j;
            float v;
            if (c < 64)       v = kp[d * 64 + c];
            else if (c < 128) v = vp[d * 64 + (c - 64)];
            else              v = qp[(size_t)(c - 128) * DIMD + d];
            HL s = bf16split(v);
            h[j] = s.h; l[j] = s.l;
        }
        *(short8*)&whi[(size_t)tid * 8] = h;
        *(short8*)&wlo[(size_t)tid * 8] = l;
    } else {
        int tid = (blk - 1184) * 256 + t;
        int lane = tid & 63, kt = (tid >> 6) & 15, mt = tid >> 10;
        int q = lane >> 4, r = lane & 15;
        const float* src = wout + (size_t)(mt * 16 + r) * DOUT + kt * 32 + q * 8;
        short8 h;
        #pragma unroll
        for (int j = 0; j < 8; ++j) h[j] = bf16rn(src[j]);
        *(short8*)&wof[(size_t)tid * 8] = h;
    }
}

// ---------------------------------------------------------------------------
// qkv_gemm: unchanged main loop; cb==1 (V) epilogue now emits the 16x16x16
// B-frag order [ic16][lane64][j4] (R20) so attn's V reads are lane-contiguous
// ds_read_b64 (zero bank conflicts; R19 had 4.19M from the 4-way pattern).
// ---------------------------------------------------------------------------
__global__ __launch_bounds__(256) void qkv_gemm(const short* __restrict__ xhi,
                                                const short* __restrict__ xlo,
                                                const short* __restrict__ whi,
                                                const short* __restrict__ wlo,
                                                short* __restrict__ khi,
                                                short* __restrict__ klo,
                                                short* __restrict__ vf,
                                                short* __restrict__ qhi,
                                                short* __restrict__ qlo) {
    __shared__ __align__(16) char pool[49152];
    short* Ah = (short*)pool;            // 8192 shorts (16 KB)
    short* Al = Ah + 8192;               // 16 KB
    short* Bh = Al + 8192;               // 4096 shorts (8 KB)
    short* Bl = Bh + 4096;               // 8 KB
    float (*Cs)[65] = (float(*)[65])pool;   // 128*65*4 = 33280 B (alias)

    // XCD swizzle: idx = (g&7) + 8*((g>>3)*10 + cb), g = M-tile id [0,64)
    const int idx = blockIdx.x;
    const int low = idx & 7, rest = idx >> 3;
    const int cb = rest % 10, gh = rest / 10;
    const int g = gh * 8 + low;
    const int b = g >> 3, bml = g & 7;      // rows n0 = bml*128

    const int tid = threadIdx.x, w = tid >> 6, lane = tid & 63;
    const int q = lane >> 4, r = lane & 15;
    f32x4 acc[2][4];
    #pragma unroll
    for (int i = 0; i < 2; ++i)
        #pragma unroll
        for (int j = 0; j < 4; ++j) acc[i][j] = (f32x4){0.f, 0.f, 0.f, 0.f};

    for (int it = 0; it < 8; ++it) {
        __syncthreads();
        for (int u = w; u < 16; u += 4) {
            size_t ga = ((size_t)((b * 64 + bml * 8 + (u >> 1)) * 16 + it * 2 + (u & 1))) * 512 + lane * 8;
            dma16(xhi + ga, &Ah[u * 512]);
            dma16(xlo + ga, &Al[u * 512]);
            if (u < 8) {
                size_t gb = ((size_t)((cb * 4 + (u >> 1)) * 16 + it * 2 + (u & 1))) * 512 + lane * 8;
                dma16(whi + gb, &Bh[u * 512]);
                dma16(wlo + gb, &Bl[u * 512]);
            }
        }
        __syncthreads();
        #pragma unroll
        for (int kc = 0; kc < 2; ++kc) {
            short8 ah[2], al[2];
            #pragma unroll
            for (int rt = 0; rt < 2; ++rt) {
                ah[rt] = *(short8*)&Ah[((w * 2 + rt) * 2 + kc) * 512 + lane * 8];
                al[rt] = *(short8*)&Al[((w * 2 + rt) * 2 + kc) * 512 + lane * 8];
            }
            #pragma unroll
            for (int tt = 0; tt < 4; ++tt) {
                short8 bh = *(short8*)&Bh[(tt * 2 + kc) * 512 + lane * 8];
                short8 bl = *(short8*)&Bl[(tt * 2 + kc) * 512 + lane * 8];
                #pragma unroll
                for (int rt = 0; rt < 2; ++rt) {
                    acc[rt][tt] = __builtin_amdgcn_mfma_f32_16x16x32_bf16(ah[rt], bh, acc[rt][tt], 0, 0, 0);
                    acc[rt][tt] = __builtin_amdgcn_mfma_f32_16x16x32_bf16(ah[rt], bl, acc[rt][tt], 0, 0, 0);
                    acc[rt][tt] = __builtin_amdgcn_mfma_f32_16x16x32_bf16(al[rt], bh, acc[rt][tt], 0, 0, 0);
                }
            }
        }
    }

    // ---- fused epilogue: C tile (128x64) -> LDS -> frag-order bf16 global ----
    __syncthreads();
    #pragma unroll
    for (int rt = 0; rt < 2; ++rt)
        #pragma unroll
        for (int reg = 0; reg < 4; ++reg)
            #pragma unroll
            for (int tt = 0; tt < 4; ++tt)
                Cs[w * 32 + rt * 16 + q * 4 + reg][tt * 16 + r] = acc[rt][tt][reg];
    __syncthreads();

    if (cb == 0) {
        // K: 2 t-tiles; elem K[m=t*64+i*16+r2][kd=cc*32+q2*8+j], ic=i*2+cc
        for (int u = tid; u < 1024; u += 256) {
            int lane2 = u & 63, ic = (u >> 6) & 7, tl = u >> 9;
            int q2 = lane2 >> 4, r2 = lane2 & 15;
            int i = ic >> 1, cc = ic & 1;
            short8 h8, l8;
            #pragma unroll
            for (int j = 0; j < 8; ++j) {
                HL s = bf16split(Cs[tl * 64 + i * 16 + r2][cc * 32 + q2 * 8 + j]);
                h8[j] = s.h; l8[j] = s.l;
            }
            size_t off = ((size_t)(b * 16 + bml * 2 + tl) * 8 + ic) * 512 + lane2 * 8;
            *(short8*)&khi[off] = h8;
            *(short8*)&klo[off] = l8;
        }
    } else if (cb == 1) {
        // V (R20): 16x16x16 B-frag order.  ic = c4*4+tv; element
        // V[key = tl*64 + c4*16 + qn*4 + j][v = tv*16 + r].  Each u writes a
        // short8 covering lane-pair (a*2, a*2+1) j-quads -> coalesced.
        for (int u = tid; u < 1024; u += 256) {
            int a = u & 31, ic = (u >> 5) & 15, tl = u >> 9;
            int c4 = ic >> 2, tv = ic & 3;
            short8 v8;
            #pragma unroll
            for (int jj = 0; jj < 8; ++jj) {
                int lane2 = a * 2 + (jj >> 2), j = jj & 3;
                int qn = lane2 >> 4, r2 = lane2 & 15;
                v8[jj] = bf16rn(Cs[tl * 64 + c4 * 16 + qn * 4 + j][tv * 16 + r2]);
            }
            size_t off = ((size_t)(b * 16 + bml * 2 + tl) * 16 + ic) * 256 + a * 8;
            *(short8*)&vf[off] = v8;
        }
    } else {
        // Q head hd: 8 nt-tiles x 2 kc = 16 chunks
        const int hd = cb - 2;
        const float qscale = 0.125f * 1.44269504f;
        for (int u = tid; u < 1024; u += 256) {
            int lane2 = u & 63, ch = u >> 6;        // ch in [0,16)
            int q2 = lane2 >> 4, r2 = lane2 & 15;
            int kc = ch & 1, ntl = ch >> 1;         // ntl in [0,8)
            short8 h8, l8;
            #pragma unroll
            for (int j = 0; j < 8; ++j) {
                HL s = bf16split(Cs[ntl * 16 + r2][kc * 32 + q2 * 8 + j] * qscale);
                h8[j] = s.h; l8[j] = s.l;
            }
            size_t off = ((((size_t)(b * 8 + hd) * 64 + bml * 8 + ntl) * 2 + kc) * 64 + lane2) * 8;
            *(short8*)&qhi[off] = h8;
            *(short8*)&qlo[off] = l8;
        }
    }
}

// ---------------------------------------------------------------------------
// attn: R20 (resubmitted R21 — prior round was a broker acquisition timeout;
// kernel never ran).  R19 post-mortem: LDS pipe still critical (~39 of
// 55.4 µs) and K/V fragment reads are 8x wave-redundant (all waves read
// identical data).  Changes: (1) 4 waves x 2 q-tiles per wave (grid stays
// 512, 256 thr): each K/V fragment is loaded from LDS ONCE into regs and
// feeds BOTH q-tiles' MFMAs -> K/V LDS traffic per q-tile halves.  (2) V
// stored in 16x16x16 B-frag order -> V reads are lane-contiguous b64, zero
// bank conflicts (R19: 4.19M conflict cycles).  Swapped-QK^T register-
// resident P unchanged.  Staging protocol (dbuf + pinned vmcnt/lgkm drain +
// 1 barrier) proven R16-R19.
// ---------------------------------------------------------------------------
__global__ __launch_bounds__(256) void attn_mfma(const short* __restrict__ qhi_g,
                                                 const short* __restrict__ qlo_g,
                                                 const short* __restrict__ khi_g,
                                                 const short* __restrict__ klo_g,
                                                 const short* __restrict__ vf_g,
                                                 short* __restrict__ ob) {
    __shared__ short Khi[2][4096], Klo[2][4096], Vf[2][4096];   // 48 KB
    const int blk = blockIdx.x;
    const int b   = blk & 7;        // XCD = blk%8 = b -> per-XCD K/V L2 locality
    const int h   = (blk >> 3) & 7;
    const int qt  = blk >> 6;
    const int tid = threadIdx.x;
    const int w    = tid >> 6;      // 4 waves
    const int lane = tid & 63;
    const int q    = lane >> 4;
    const int r    = lane & 15;

    short8 qhi[2][2], qlo[2][2];    // [rt][c]
    #pragma unroll
    for (int rt = 0; rt < 2; ++rt) {
        const int nt = qt * 8 + w * 2 + rt;
        #pragma unroll
        for (int c = 0; c < 2; ++c) {
            size_t off = ((((size_t)(b * 8 + h) * 64 + nt) * 2 + c) * 64 + lane) * 8;
            qhi[rt][c] = *(const short8*)&qhi_g[off];
            qlo[rt][c] = *(const short8*)&qlo_g[off];
        }
    }

    short4v bones4;
    #pragma unroll
    for (int j = 0; j < 4; ++j) bones4[j] = (short)0x3F80;

    f32x4 oacc[2][4], lacc[2];
    float m_[2];
    #pragma unroll
    for (int rt = 0; rt < 2; ++rt) {
        #pragma unroll
        for (int tt = 0; tt < 4; ++tt) oacc[rt][tt] = (f32x4){0.f, 0.f, 0.f, 0.f};
        lacc[rt] = (f32x4){0.f, 0.f, 0.f, 0.f};
        m_[rt] = -1e30f;
    }

    const int kbase = lane * 8;     // K frag base (shorts)
    const int vbase = lane * 4;     // V frag base (shorts) — lane-contiguous

    // prologue: DMA tile 0 into buffer 0 (each wave stages chunks w, w+4)
    {
        const size_t kb = ((size_t)(b * 16 + 0) * 8) * 512;
        #pragma unroll
        for (int ch0 = 0; ch0 < 2; ++ch0) {
            int ch = w + ch0 * 4;
            dma16(khi_g + kb + ch * 512 + lane * 8, &Khi[0][ch * 512]);
            dma16(klo_g + kb + ch * 512 + lane * 8, &Klo[0][ch * 512]);
            dma16(vf_g  + kb + ch * 512 + lane * 8, &Vf [0][ch * 512]);
        }
    }

    for (int t = 0; t < 16; ++t) {
        const int cur = t & 1;
        // pinned drain (proven R16): own DMA landed + own ds_reads retired,
        // then barrier makes it workgroup-wide.
        __builtin_amdgcn_sched_barrier(0);
        asm volatile("s_waitcnt vmcnt(0) lgkmcnt(0)" ::: "memory");
        __builtin_amdgcn_sched_barrier(0);
        __syncthreads();
        if (t < 15) {               // issue next tile into buf[cur^1]
            const size_t kb = ((size_t)(b * 16 + t + 1) * 8) * 512;
            #pragma unroll
            for (int ch0 = 0; ch0 < 2; ++ch0) {
                int ch = w + ch0 * 4;
                dma16(khi_g + kb + ch * 512 + lane * 8, &Khi[cur ^ 1][ch * 512]);
                dma16(klo_g + kb + ch * 512 + lane * 8, &Klo[cur ^ 1][ch * 512]);
                dma16(vf_g  + kb + ch * 512 + lane * 8, &Vf [cur ^ 1][ch * 512]);
            }
        }

        // ---- swapped QK^T: each K frag read once, feeds both q-tiles ----
        // sT[rt][i] lane(q,r) reg: S[key=i*16+q*4+reg][row=r] (split-bf16)
        f32x4 sT[2][4];
        #pragma unroll
        for (int rt = 0; rt < 2; ++rt)
            #pragma unroll
            for (int i = 0; i < 4; ++i) sT[rt][i] = (f32x4){0.f, 0.f, 0.f, 0.f};
        #pragma unroll
        for (int cc = 0; cc < 2; ++cc) {
            #pragma unroll
            for (int i = 0; i < 4; ++i) {
                short8 kh = *(short8*)&Khi[cur][(i * 2 + cc) * 512 + kbase];
                short8 kl = *(short8*)&Klo[cur][(i * 2 + cc) * 512 + kbase];
                #pragma unroll
                for (int rt = 0; rt < 2; ++rt) {
                    sT[rt][i] = __builtin_amdgcn_mfma_f32_16x16x32_bf16(kh, qhi[rt][cc], sT[rt][i], 0, 0, 0);
                    sT[rt][i] = __builtin_amdgcn_mfma_f32_16x16x32_bf16(kl, qhi[rt][cc], sT[rt][i], 0, 0, 0);
                    sT[rt][i] = __builtin_amdgcn_mfma_f32_16x16x32_bf16(kh, qlo[rt][cc], sT[rt][i], 0, 0, 0);
                }
            }
        }

        // ---- lazy online softmax (log2 space; m_ scalar per lane = row r) ----
        float pm[2];
        #pragma unroll
        for (int rt = 0; rt < 2; ++rt) {
            float a0 = fmaxf(fmaxf(sT[rt][0][0], sT[rt][0][1]), fmaxf(sT[rt][0][2], sT[rt][0][3]));
            float a1 = fmaxf(fmaxf(sT[rt][1][0], sT[rt][1][1]), fmaxf(sT[rt][1][2], sT[rt][1][3]));
            float a2 = fmaxf(fmaxf(sT[rt][2][0], sT[rt][2][1]), fmaxf(sT[rt][2][2], sT[rt][2][3]));
            float a3 = fmaxf(fmaxf(sT[rt][3][0], sT[rt][3][1]), fmaxf(sT[rt][3][2], sT[rt][3][3]));
            pm[rt] = fmaxf(fmaxf(a0, a1), fmaxf(a2, a3));
        }
        bool need = (pm[0] > m_[0] + 30.f) || (pm[1] > m_[1] + 30.f);
        if (__any((int)need)) {
            #pragma unroll
            for (int rt = 0; rt < 2; ++rt) {
                float full = fmaxf(pm[rt], __shfl_xor(pm[rt], 16));
                full = fmaxf(full, __shfl_xor(full, 32));
                float nm = fmaxf(m_[rt], full);
                float alpha = exp2f(m_[rt] - nm);
                m_[rt] = nm;
                #pragma unroll
                for (int reg = 0; reg < 4; ++reg) {
                    float areg = __shfl(alpha, q * 20 + reg);
                    lacc[rt][reg] *= areg;
                    #pragma unroll
                    for (int tt = 0; tt < 4; ++tt) oacc[rt][tt][reg] *= areg;
                }
            }
        }
        #pragma unroll
        for (int rt = 0; rt < 2; ++rt)
            #pragma unroll
            for (int i = 0; i < 4; ++i)
                #pragma unroll
                for (int reg = 0; reg < 4; ++reg)
                    sT[rt][i][reg] = exp2f(sT[rt][i][reg] - m_[rt]);

        // ---- PV: each V frag read once, feeds both q-tiles ----
        #pragma unroll
        for (int c = 0; c < 4; ++c) {
            short4v pf[2];
            #pragma unroll
            for (int rt = 0; rt < 2; ++rt) {
                union { uint2 u; short4v s; } pk;
                pk.u.x = packbf2(sT[rt][c][0], sT[rt][c][1]);
                pk.u.y = packbf2(sT[rt][c][2], sT[rt][c][3]);
                pf[rt] = pk.s;
                lacc[rt] = mfma16(pf[rt], bones4, lacc[rt]);
            }
            #pragma unroll
            for (int tt = 0; tt < 4; ++tt) {
                short4v vfr = *(const short4v*)&Vf[cur][(c * 4 + tt) * 256 + vbase];
                #pragma unroll
                for (int rt = 0; rt < 2; ++rt)
                    oacc[rt][tt] = mfma16(pf[rt], vfr, oacc[rt][tt]);
            }
        }
    }

    // hazard guard for the inline-asm MFMA fallback (MFMA write -> VALU read)
    asm volatile("s_nop 7\n\ts_nop 7" :::);

    // ---- epilogue: O frag-order bf16 store (D layout unchanged) ----
    #pragma unroll
    for (int rt = 0; rt < 2; ++rt) {
        const int nt = qt * 8 + w * 2 + rt;
        #pragma unroll
        for (int reg = 0; reg < 4; ++reg) {
            float inv = 1.f / lacc[rt][reg];
            #pragma unroll
            for (int tt = 0; tt < 4; ++tt) {
                int ct = h * 2 + (tt >> 1);
                int lanep = ((tt & 1) * 2 + (r >> 3)) * 16 + q * 4 + reg;
                ob[((((size_t)b * 64 + nt) * 16 + ct) * 64 + lanep) * 8 + (r & 7)] =
                    bf16rn(oacc[rt][tt][reg] * inv);
            }
        }
    }
}

// ---------------------------------------------------------------------------
// out_gemm: plain bf16 MFMA, double-buffered staging (unchanged).
// ---------------------------------------------------------------------------
__global__ __launch_bounds__(256) void out_gemm(const short* __restrict__ wof,
                                                const short* __restrict__ obf,
                                                float* __restrict__ out) {
    __shared__ short Ah[2][4096];
    __shared__ short Bh[2][4096];
    const int b = blockIdx.z, bd = blockIdx.y, bn = blockIdx.x;
    const int tid = threadIdx.x, w = tid >> 6, lane = tid & 63;
    const int q = lane >> 4, r = lane & 15;
    f32x4 acc[4];
    #pragma unroll
    for (int j = 0; j < 4; ++j) acc[j] = (f32x4){0.f, 0.f, 0.f, 0.f};

    for (int u = w; u < 8; u += 4) {
        size_t ga = ((size_t)((bd * 4 + (u >> 1)) * 16 + (u & 1))) * 512 + lane * 8;
        dma16(wof + ga, &Ah[0][u * 512]);
        size_t gb = ((size_t)((b * 64 + bn * 4 + (u >> 1)) * 16 + (u & 1))) * 512 + lane * 8;
        dma16(obf + gb, &Bh[0][u * 512]);
    }

    for (int it = 0; it < 8; ++it) {
        const int cur = it & 1;
        __syncthreads();
        if (it < 7) {
            for (int u = w; u < 8; u += 4) {
                size_t ga = ((size_t)((bd * 4 + (u >> 1)) * 16 + (it + 1) * 2 + (u & 1))) * 512 + lane * 8;
                dma16(wof + ga, &Ah[cur ^ 1][u * 512]);
                size_t gb = ((size_t)((b * 64 + bn * 4 + (u >> 1)) * 16 + (it + 1) * 2 + (u & 1))) * 512 + lane * 8;
                dma16(obf + gb, &Bh[cur ^ 1][u * 512]);
            }
        }
        #pragma unroll
        for (int kc = 0; kc < 2; ++kc) {
            short8 a = *(short8*)&Ah[cur][(w * 2 + kc) * 512 + lane * 8];
            #pragma unroll
            for (int tt = 0; tt < 4; ++tt) {
                short8 bb = *(short8*)&Bh[cur][(tt * 2 + kc) * 512 + lane * 8];
                acc[tt] = __builtin_amdgcn_mfma_f32_16x16x32_bf16(a, bb, acc[tt], 0, 0, 0);
            }
        }
    }
    const int d_base = bd * 64 + w * 16;
    #pragma unroll
    for (int reg = 0; reg < 4; ++reg)
        #pragma unroll
        for (int tt = 0; tt < 4; ++tt)
            out[((size_t)b * DOUT + d_base + q * 4 + reg) * NTOK
                + bn * 64 + tt * 16 + r] = acc[tt][reg];
}

// ---------------------------------------------------------------------------
extern "C" void kernel_launch(void* const* d_in, const int* in_sizes, int n_in,
                              void* d_out, int out_size, void* d_ws, size_t ws_size,
                              hipStream_t stream) {
    const float* x  = (const float*)d_in[0];
    const float* qp = (const float*)d_in[1];
    const float* kp = (const float*)d_in[2];
    const float* vp = (const float*)d_in[3];
    const float* op = (const float*)d_in[4];
    float* out = (float*)d_out;

    // workspace: 38.5 MB (proven R12/R13)
    short* Whi = (short*)d_ws;                 // 327,680
    short* Wlo = Whi + 327680;                 // 327,680
    short* Xhi = Wlo + 327680;                 // 4,194,304
    short* Xlo = Xhi + 4194304;                // 4,194,304
    short* Qhi = Xlo + 4194304;                // 4,194,304
    short* Qlo = Qhi + 4194304;                // 4,194,304
    short* Khi = Qlo + 4194304;                // 524,288
    short* Klo = Khi + 524288;                 // 524,288
    short* Vf  = Klo + 524288;                 // 524,288
    short* Wof = Vf  + 524288;                 // 262,144
    short* Ob  = Xhi;                          // alias: X dead after qkv_gemm

    prepack_all <<<1312, 256, 0, stream>>>(x, qp, kp, vp, op,
                                           Whi, Wlo, Xhi, Xlo, Wof);
    qkv_gemm    <<<640, 256, 0, stream>>>(Xhi, Xlo, Whi, Wlo,
                                          Khi, Klo, Vf, Qhi, Qlo);
    attn_mfma   <<<512, 256, 0, stream>>>(Qhi, Qlo, Khi, Klo, Vf, Ob);
    out_gemm    <<<dim3(16, 8, BATCH), 256, 0, stream>>>(Wof, Ob, out);
}